// Round 13
// baseline (386.068 us; speedup 1.0000x reference)
//
#include <hip/hip_runtime.h>
#include <hip/hip_bf16.h>

// THLSTM cell fused, MI355X gfx950 — round 13.
// r9's lean wave (1 acc, cacc[16]+ipk[8], arch 64 + agpr 64 -> 4 waves/SIMD)
// in a 4-wave WG covering 32 rows x 128 cols (grid = 2048 row-blocks x 2
// col-halves = 4096 WGs). LDS 40KB -> 4 independent WGs/CU (vs r9's 2):
// staging/epilogue HBM of one WG overlaps GEMM of the others.
// Each WG computes the FULL 256-col s (needed in K-dim) = +11% GEMM work.

constexpr int Btot = 65536;
constexpr int H    = 256;
constexpr int I    = 128;
constexpr int K1   = 384;    // [h|x]
constexpr int BT   = 32;     // batch rows per WG
constexpr int NTHR = 256;    // 4 waves
constexpr int SOFF = 24576;  // s base: 48 k8 x 32 rows x 16B

typedef __bf16 bf16x8  __attribute__((ext_vector_type(8)));
typedef float  f32x16  __attribute__((ext_vector_type(16)));
typedef unsigned short ushort8 __attribute__((ext_vector_type(8)));

__device__ __forceinline__ unsigned short f2bf(float f) {
    unsigned u = __builtin_bit_cast(unsigned, f);
    u += 0x7fffu + ((u >> 16) & 1u);   // RNE
    return (unsigned short)(u >> 16);
}
__device__ __forceinline__ float bf2f(unsigned short s) {
    return __builtin_bit_cast(float, ((unsigned)s) << 16);
}
__device__ __forceinline__ float sigm(float x) {
    return __builtin_amdgcn_rcpf(1.0f + exp2f(-1.4426950408889634f * x));
}
__device__ __forceinline__ float tanh_f(float x) {
    return 1.0f - 2.0f * __builtin_amdgcn_rcpf(1.0f + exp2f(2.8853900817779268f * x));
}

// Weights bf16, layout [k8][col][8]: elem (col, k=k8*8+e) at (k8*256+col)*8+e.
// w0: 48 k8 (K=384); per gate wg: 80 k8 (K=640: h|x|s), gates f,i,T,u,o.
__global__ void convert_w(const float* __restrict__ Wh, const float* __restrict__ Wx,
                          const float* __restrict__ Ws, unsigned short* __restrict__ w0,
                          unsigned short* __restrict__ wg) {
    const int t  = blockIdx.x * blockDim.x + threadIdx.x;
    const int N0 = 48 * 2048;        // 98304
    const int N1 = 5 * 80 * 2048;    // 819200
    if (t < N0) {
        const int k8 = t >> 11, rem = t & 2047;
        const int col = rem >> 3, e = rem & 7;
        const int k = k8 * 8 + e;
        const float v = (k < H) ? Wh[col * H + k] : Wx[col * I + (k - H)];
        w0[t] = f2bf(v);
    } else if (t < N0 + N1) {
        const int u   = t - N0;
        const int g1  = u / 163840;
        const int rem = u - g1 * 163840;
        const int k8  = rem >> 11;
        const int r2  = rem & 2047;
        const int col = r2 >> 3, e = r2 & 7;
        const int k   = k8 * 8 + e;
        const int g   = g1 + 1;
        float v;
        if (k < H)        v = Wh[g * H * H + col * H + k];
        else if (k < K1)  v = Wx[g * H * I + col * I + (k - H)];
        else              v = Ws[g1 * H * H + col * H + (k - K1)];
        wg[u] = f2bf(v);
    }
}

// K-loop: 1 A stream, 1 B stream, single acc chain. Ring depth 2.
template<int NIT>
__device__ __forceinline__ void gemm1(const unsigned char* Ab, int abase,
        const unsigned short* __restrict__ Wp, f32x16& acc) {
    bf16x8 b[2], a[2];
    #pragma unroll
    for (int i = 0; i < 2; ++i) {
        b[i] = *(const bf16x8*)(Wp + i * 4096);
        a[i] = *(const bf16x8*)(Ab + abase + i * 1024);
    }
    #pragma unroll
    for (int i = 0; i < NIT; ++i) {
        const bf16x8 av = a[i & 1], bv = b[i & 1];
        if (i + 2 < NIT) {
            a[i & 1] = *(const bf16x8*)(Ab + abase + (i + 2) * 1024);
            b[i & 1] = *(const bf16x8*)(Wp + (i + 2) * 4096);
        }
        acc = __builtin_amdgcn_mfma_f32_32x32x16_bf16(av, bv, acc, 0, 0, 0);
    }
}

__global__ __launch_bounds__(NTHR, 4) void thlstm_fused(
        const float* __restrict__ x_t, const float* __restrict__ delta_t,
        const float* __restrict__ h_prev, const float* __restrict__ c_prev,
        const float* __restrict__ Wst, const float* __restrict__ bias,
        const unsigned short* __restrict__ w0, const unsigned short* __restrict__ wg,
        float* __restrict__ out) {
    __shared__ __align__(16) unsigned char Abuf[40960];   // 24KB hx + 16KB s
    const int tid  = threadIdx.x;
    const int wgid = blockIdx.x;
    const int b0   = (wgid >> 1) * BT;     // row block
    const int ch   = wgid & 1;             // column half: cols ch*128..+127

    // ---- stage h|x bf16: chunk (k8, row) at (k8*32+row)*16 ----
    #pragma unroll
    for (int it = 0; it < 6; ++it) {
        const int c   = it * NTHR + tid;
        const int k8  = c >> 5, row = c & 31;
        const float* src = (k8 < 32) ? (h_prev + (size_t)(b0 + row) * H + k8 * 8)
                                     : (x_t    + (size_t)(b0 + row) * I + (k8 - 32) * 8);
        const float4 v0 = ((const float4*)src)[0];
        const float4 v1 = ((const float4*)src)[1];
        ushort8 p;
        p[0] = f2bf(v0.x); p[1] = f2bf(v0.y); p[2] = f2bf(v0.z); p[3] = f2bf(v0.w);
        p[4] = f2bf(v1.x); p[5] = f2bf(v1.y); p[6] = f2bf(v1.z); p[7] = f2bf(v1.w);
        *(ushort8*)(Abuf + (k8 * 32 + row) * 16) = p;
    }
    __syncthreads();

    const int lane  = tid & 63;
    const int wv    = tid >> 6;            // 0..3
    const int half  = lane >> 5;
    const int l31   = lane & 31;
    const int rbase = 4 * half;
    const int abase = half * 512 + l31 * 16;

    // ---- gate s: FULL 256 cols (this WG computes all of s; cols wv*64..+63) ----
    #pragma unroll
    for (int sl = 0; sl < 2; ++sl) {
        const int oc = wv * 64 + sl * 32 + l31;
        f32x16 acc;
        #pragma unroll
        for (int r = 0; r < 16; ++r) acc[r] = 0.f;
        gemm1<24>(Abuf, abase, w0 + half * 2048 + oc * 8, acc);
        const float wst = Wst[oc];
        const float bs  = bias[oc];
        const int sb = SOFF + (oc >> 3) * 512 + (oc & 7) * 2;
        #pragma unroll
        for (int r = 0; r < 16; ++r) {
            const int mrow = (r & 3) + 8 * (r >> 2) + rbase;
            const float sv = tanh_f(acc[r] + delta_t[b0 + mrow] * wst + bs);
            *(unsigned short*)(Abuf + sb + mrow * 16) = f2bf(sv);
        }
    }
    __syncthreads();

    const int ocol  = ch * 128 + wv * 32 + l31;
    const int wlo   = half * 2048 + ocol * 8;   // shorts
    const int sbase = SOFF + (ocol >> 3) * 512 + (ocol & 7) * 2;

    float    cacc[16];
    unsigned ipk[8];

    // ---- gate f (wg 0, bias 1): c = f * c_prev ----
    {
        f32x16 ac;
        #pragma unroll
        for (int r = 0; r < 16; ++r) ac[r] = 0.f;
        gemm1<40>(Abuf, abase, wg + 0 * 163840 + wlo, ac);
        const float bg = bias[1 * H + ocol];
        #pragma unroll
        for (int r = 0; r < 16; ++r) {
            const int mrow = (r & 3) + 8 * (r >> 2) + rbase;
            const size_t idx = (size_t)(b0 + mrow) * H + ocol;
            cacc[r] = sigm(ac[r] + bg) * c_prev[idx];
        }
    }
    // ---- gate T (wg 2, bias 3): c += T * s (s from LDS) ----
    {
        f32x16 ac;
        #pragma unroll
        for (int r = 0; r < 16; ++r) ac[r] = 0.f;
        gemm1<40>(Abuf, abase, wg + 2 * 163840 + wlo, ac);
        const float bg = bias[3 * H + ocol];
        #pragma unroll
        for (int r = 0; r < 16; ++r) {
            const int mrow = (r & 3) + 8 * (r >> 2) + rbase;
            const float sv = bf2f(*(const unsigned short*)(Abuf + sbase + mrow * 16));
            cacc[r] += sigm(ac[r] + bg) * sv;
        }
    }
    // ---- gate i (wg 1, bias 2): keep packed ----
    {
        f32x16 ac;
        #pragma unroll
        for (int r = 0; r < 16; ++r) ac[r] = 0.f;
        gemm1<40>(Abuf, abase, wg + 1 * 163840 + wlo, ac);
        const float bg = bias[2 * H + ocol];
        float tmpf = 0.f;
        #pragma unroll
        for (int r = 0; r < 16; ++r) {
            const float sg = sigm(ac[r] + bg);
            if ((r & 1) == 0) tmpf = sg;
            else ipk[r >> 1] = (unsigned)f2bf(tmpf) | ((unsigned)f2bf(sg) << 16);
        }
    }
    // ---- gate u (wg 3, bias 4): c += i * tanh(u) ----
    {
        f32x16 ac;
        #pragma unroll
        for (int r = 0; r < 16; ++r) ac[r] = 0.f;
        gemm1<40>(Abuf, abase, wg + 3 * 163840 + wlo, ac);
        const float bg = bias[4 * H + ocol];
        #pragma unroll
        for (int r = 0; r < 16; ++r) {
            const float iv = bf2f((unsigned short)((ipk[r >> 1] >> ((r & 1) * 16)) & 0xffffu));
            cacc[r] += iv * tanh_f(ac[r] + bg);
        }
    }
    // ---- gate o (wg 4, bias 5): outputs ----
    {
        f32x16 ac;
        #pragma unroll
        for (int r = 0; r < 16; ++r) ac[r] = 0.f;
        gemm1<40>(Abuf, abase, wg + 4 * 163840 + wlo, ac);
        const float bg = bias[5 * H + ocol];
        #pragma unroll
        for (int r = 0; r < 16; ++r) {
            const int mrow = (r & 3) + 8 * (r >> 2) + rbase;
            const size_t idx = (size_t)(b0 + mrow) * H + ocol;
            const float c = cacc[r];
            out[idx] = sigm(ac[r] + bg) * tanh_f(c);
            out[(size_t)Btot * H + idx] = c;
        }
    }
}

extern "C" void kernel_launch(void* const* d_in, const int* in_sizes, int n_in,
                              void* d_out, int out_size, void* d_ws, size_t ws_size,
                              hipStream_t stream) {
    (void)in_sizes; (void)n_in; (void)out_size; (void)ws_size;
    const float* x_t    = (const float*)d_in[0];
    const float* delta  = (const float*)d_in[1];
    const float* h_prev = (const float*)d_in[2];
    const float* c_prev = (const float*)d_in[3];
    const float* Wh     = (const float*)d_in[4];
    const float* Wx     = (const float*)d_in[5];
    const float* Ws     = (const float*)d_in[6];
    const float* Wst    = (const float*)d_in[7];
    const float* bias   = (const float*)d_in[8];
    float* out = (float*)d_out;

    unsigned short* w0 = (unsigned short*)d_ws;   // 48*2048 bf16
    unsigned short* wg = w0 + 48 * 2048;          // 5*80*2048 bf16

    const int total = 48 * 2048 + 5 * 80 * 2048;  // 917504
    convert_w<<<(total + 255) / 256, 256, 0, stream>>>(Wh, Wx, Ws, w0, wg);
    thlstm_fused<<<(Btot / BT) * 2, NTHR, 0, stream>>>(x_t, delta, h_prev, c_prev,
                                                       Wst, bias, w0, wg, out);
}

// Round 15
// 211.286 us; speedup vs baseline: 1.8272x; 1.8272x over previous
//
#include <hip/hip_runtime.h>
#include <hip/hip_bf16.h>

// THLSTM cell fused, MI355X gfx950 — round 15 (r14 compile-fixed).
// = round 9 (best: 209us, lean wave, 4 waves/SIMD, 2 WGs/CU) + nontemporal
// hints on ALL streaming traffic (h/x staging, c_prev, out stores).
// Theory: streaming 300MB through L2 evicts the 1.84MB weight set ->
// B-loads miss to L3/HBM (~900cy) -> 560cy/iter stalls. 'nt' keeps
// weights L2-resident -> B-latency ~200cy -> MFMA util up.

constexpr int Btot = 65536;
constexpr int H    = 256;
constexpr int I    = 128;
constexpr int K1   = 384;    // [h|x]
constexpr int BT   = 32;     // batch rows per WG
constexpr int NTHR = 512;    // 8 waves
constexpr int SOFF = 24576;  // s-tile base: 48 k8 x 32 rows x 16B

typedef __bf16 bf16x8  __attribute__((ext_vector_type(8)));
typedef float  f32x16  __attribute__((ext_vector_type(16)));
typedef float  f32x4v  __attribute__((ext_vector_type(4)));
typedef unsigned short ushort8 __attribute__((ext_vector_type(8)));

__device__ __forceinline__ unsigned short f2bf(float f) {
    unsigned u = __builtin_bit_cast(unsigned, f);
    u += 0x7fffu + ((u >> 16) & 1u);   // RNE
    return (unsigned short)(u >> 16);
}
__device__ __forceinline__ float bf2f(unsigned short s) {
    return __builtin_bit_cast(float, ((unsigned)s) << 16);
}
__device__ __forceinline__ float sigm(float x) {
    return __builtin_amdgcn_rcpf(1.0f + exp2f(-1.4426950408889634f * x));
}
__device__ __forceinline__ float tanh_f(float x) {
    return 1.0f - 2.0f * __builtin_amdgcn_rcpf(1.0f + exp2f(2.8853900817779268f * x));
}

// Weights bf16, layout [k8][col][8]: elem (col, k=k8*8+e) at (k8*256+col)*8+e.
// w0: 48 k8 (K=384); per gate wg: 80 k8 (K=640: h|x|s), gates f,i,T,u,o.
__global__ void convert_w(const float* __restrict__ Wh, const float* __restrict__ Wx,
                          const float* __restrict__ Ws, unsigned short* __restrict__ w0,
                          unsigned short* __restrict__ wg) {
    const int t  = blockIdx.x * blockDim.x + threadIdx.x;
    const int N0 = 48 * 2048;        // 98304
    const int N1 = 5 * 80 * 2048;    // 819200
    if (t < N0) {
        const int k8 = t >> 11, rem = t & 2047;
        const int col = rem >> 3, e = rem & 7;
        const int k = k8 * 8 + e;
        const float v = (k < H) ? Wh[col * H + k] : Wx[col * I + (k - H)];
        w0[t] = f2bf(v);
    } else if (t < N0 + N1) {
        const int u   = t - N0;
        const int g1  = u / 163840;
        const int rem = u - g1 * 163840;
        const int k8  = rem >> 11;
        const int r2  = rem & 2047;
        const int col = r2 >> 3, e = r2 & 7;
        const int k   = k8 * 8 + e;
        const int g   = g1 + 1;
        float v;
        if (k < H)        v = Wh[g * H * H + col * H + k];
        else if (k < K1)  v = Wx[g * H * I + col * I + (k - H)];
        else              v = Ws[g1 * H * H + col * H + (k - K1)];
        wg[u] = f2bf(v);
    }
}

// K-loop: 1 A stream, 1 B stream, single acc chain. Ring depth 2.
template<int NIT>
__device__ __forceinline__ void gemm1(const unsigned char* Ab, int abase,
        const unsigned short* __restrict__ Wp, f32x16& acc) {
    bf16x8 b[2], a[2];
    #pragma unroll
    for (int i = 0; i < 2; ++i) {
        b[i] = *(const bf16x8*)(Wp + i * 4096);
        a[i] = *(const bf16x8*)(Ab + abase + i * 1024);
    }
    #pragma unroll
    for (int i = 0; i < NIT; ++i) {
        const bf16x8 av = a[i & 1], bv = b[i & 1];
        if (i + 2 < NIT) {
            a[i & 1] = *(const bf16x8*)(Ab + abase + (i + 2) * 1024);
            b[i & 1] = *(const bf16x8*)(Wp + (i + 2) * 4096);
        }
        acc = __builtin_amdgcn_mfma_f32_32x32x16_bf16(av, bv, acc, 0, 0, 0);
    }
}

__global__ __launch_bounds__(NTHR, 4) void thlstm_fused(
        const float* __restrict__ x_t, const float* __restrict__ delta_t,
        const float* __restrict__ h_prev, const float* __restrict__ c_prev,
        const float* __restrict__ Wst, const float* __restrict__ bias,
        const unsigned short* __restrict__ w0, const unsigned short* __restrict__ wg,
        float* __restrict__ out) {
    __shared__ __align__(16) unsigned char Abuf[40960];   // 24KB hx + 16KB s
    const int tid = threadIdx.x;
    const int b0  = blockIdx.x * BT;

    // ---- stage h|x bf16 (nontemporal loads): chunk (k8, row) at (k8*32+row)*16
    #pragma unroll
    for (int it = 0; it < 3; ++it) {
        const int c   = it * NTHR + tid;
        const int k8  = c >> 5, row = c & 31;
        const float* src = (k8 < 32) ? (h_prev + (size_t)(b0 + row) * H + k8 * 8)
                                     : (x_t    + (size_t)(b0 + row) * I + (k8 - 32) * 8);
        const f32x4v v0 = __builtin_nontemporal_load((const f32x4v*)src);
        const f32x4v v1 = __builtin_nontemporal_load(((const f32x4v*)src) + 1);
        ushort8 p;
        p[0] = f2bf(v0[0]); p[1] = f2bf(v0[1]); p[2] = f2bf(v0[2]); p[3] = f2bf(v0[3]);
        p[4] = f2bf(v1[0]); p[5] = f2bf(v1[1]); p[6] = f2bf(v1[2]); p[7] = f2bf(v1[3]);
        *(ushort8*)(Abuf + (k8 * 32 + row) * 16) = p;
    }
    __syncthreads();

    const int lane  = tid & 63;
    const int wv    = tid >> 6;           // 0..7 -> cols wv*32 .. wv*32+31
    const int half  = lane >> 5;
    const int l31   = lane & 31;
    const int ocol  = wv * 32 + l31;
    const int rbase = 4 * half;
    const int abase = half * 512 + l31 * 16;
    const int wlo   = half * 2048 + ocol * 8;                       // shorts
    const int sbase = SOFF + ((ocol >> 3) * 32) * 16 + (ocol & 7) * 2;

    // ---- gate s: K=384 ----
    {
        f32x16 acc;
        #pragma unroll
        for (int r = 0; r < 16; ++r) acc[r] = 0.f;
        gemm1<24>(Abuf, abase, w0 + wlo, acc);
        const float wst = Wst[ocol];
        const float bs  = bias[ocol];
        #pragma unroll
        for (int r = 0; r < 16; ++r) {
            const int mrow = (r & 3) + 8 * (r >> 2) + rbase;
            const float sv = tanh_f(acc[r] + delta_t[b0 + mrow] * wst + bs);
            *(unsigned short*)(Abuf + sbase + mrow * 16) = f2bf(sv);
        }
    }
    __syncthreads();

    float    cacc[16];
    unsigned ipk[8];

    // ---- gate f (wg 0, bias 1): c = f * c_prev (nontemporal) ----
    {
        f32x16 ac;
        #pragma unroll
        for (int r = 0; r < 16; ++r) ac[r] = 0.f;
        gemm1<40>(Abuf, abase, wg + 0 * 163840 + wlo, ac);
        const float bg = bias[1 * H + ocol];
        #pragma unroll
        for (int r = 0; r < 16; ++r) {
            const int mrow = (r & 3) + 8 * (r >> 2) + rbase;
            const size_t idx = (size_t)(b0 + mrow) * H + ocol;
            cacc[r] = sigm(ac[r] + bg) * __builtin_nontemporal_load(&c_prev[idx]);
        }
    }
    // ---- gate T (wg 2, bias 3): c += T * s (s from LDS) ----
    {
        f32x16 ac;
        #pragma unroll
        for (int r = 0; r < 16; ++r) ac[r] = 0.f;
        gemm1<40>(Abuf, abase, wg + 2 * 163840 + wlo, ac);
        const float bg = bias[3 * H + ocol];
        #pragma unroll
        for (int r = 0; r < 16; ++r) {
            const int mrow = (r & 3) + 8 * (r >> 2) + rbase;
            const float sv = bf2f(*(const unsigned short*)(Abuf + sbase + mrow * 16));
            cacc[r] += sigm(ac[r] + bg) * sv;
        }
    }
    // ---- gate i (wg 1, bias 2): keep packed ----
    {
        f32x16 ac;
        #pragma unroll
        for (int r = 0; r < 16; ++r) ac[r] = 0.f;
        gemm1<40>(Abuf, abase, wg + 1 * 163840 + wlo, ac);
        const float bg = bias[2 * H + ocol];
        float tmpf = 0.f;
        #pragma unroll
        for (int r = 0; r < 16; ++r) {
            const float sg = sigm(ac[r] + bg);
            if ((r & 1) == 0) tmpf = sg;
            else ipk[r >> 1] = (unsigned)f2bf(tmpf) | ((unsigned)f2bf(sg) << 16);
        }
    }
    // ---- gate u (wg 3, bias 4): c += i * tanh(u) ----
    {
        f32x16 ac;
        #pragma unroll
        for (int r = 0; r < 16; ++r) ac[r] = 0.f;
        gemm1<40>(Abuf, abase, wg + 3 * 163840 + wlo, ac);
        const float bg = bias[4 * H + ocol];
        #pragma unroll
        for (int r = 0; r < 16; ++r) {
            const float iv = bf2f((unsigned short)((ipk[r >> 1] >> ((r & 1) * 16)) & 0xffffu));
            cacc[r] += iv * tanh_f(ac[r] + bg);
        }
    }
    // ---- gate o (wg 4, bias 5): outputs (nontemporal stores) ----
    {
        f32x16 ac;
        #pragma unroll
        for (int r = 0; r < 16; ++r) ac[r] = 0.f;
        gemm1<40>(Abuf, abase, wg + 4 * 163840 + wlo, ac);
        const float bg = bias[5 * H + ocol];
        #pragma unroll
        for (int r = 0; r < 16; ++r) {
            const int mrow = (r & 3) + 8 * (r >> 2) + rbase;
            const size_t idx = (size_t)(b0 + mrow) * H + ocol;
            const float c = cacc[r];
            __builtin_nontemporal_store(sigm(ac[r] + bg) * tanh_f(c), &out[idx]);
            __builtin_nontemporal_store(c, &out[(size_t)Btot * H + idx]);
        }
    }
}

extern "C" void kernel_launch(void* const* d_in, const int* in_sizes, int n_in,
                              void* d_out, int out_size, void* d_ws, size_t ws_size,
                              hipStream_t stream) {
    (void)in_sizes; (void)n_in; (void)out_size; (void)ws_size;
    const float* x_t    = (const float*)d_in[0];
    const float* delta  = (const float*)d_in[1];
    const float* h_prev = (const float*)d_in[2];
    const float* c_prev = (const float*)d_in[3];
    const float* Wh     = (const float*)d_in[4];
    const float* Wx     = (const float*)d_in[5];
    const float* Ws     = (const float*)d_in[6];
    const float* Wst    = (const float*)d_in[7];
    const float* bias   = (const float*)d_in[8];
    float* out = (float*)d_out;

    unsigned short* w0 = (unsigned short*)d_ws;   // 48*2048 bf16
    unsigned short* wg = w0 + 48 * 2048;          // 5*80*2048 bf16

    const int total = 48 * 2048 + 5 * 80 * 2048;  // 917504
    convert_w<<<(total + 255) / 256, 256, 0, stream>>>(Wh, Wx, Ws, w0, wg);
    thlstm_fused<<<Btot / BT, NTHR, 0, stream>>>(x_t, delta, h_prev, c_prev,
                                                 Wst, bias, w0, wg, out);
}